// Round 1
// baseline (101.024 us; speedup 1.0000x reference)
//
#include <hip/hip_runtime.h>
#include <math.h>

// NCE loss: scalar output.
//   s_j = (q_j . r_j + bias[t_j]) / E
//   loss = sum_j log_sigmoid(s_j - log(NC*freq[t_j]))
//   noise_loss = sum_j sum_k log_sigmoid(-(s_j - log(NC*freq[noises[j + k*B]])))
//   out = -(loss + noise_loss)/B + 10*(sum q^2 + sum r^2)/(E*B)

__device__ __forceinline__ float log_sigmoid_f(float x) {
    // jax.nn.log_sigmoid(x) = -softplus(-x) = min(x,0) - log1p(exp(-|x|))
    return fminf(x, 0.0f) - log1pf(expf(-fabsf(x)));
}

__global__ __launch_bounds__(256) void nce_pairs_kernel(
    const float* __restrict__ embed,
    const float* __restrict__ bias,
    const float* __restrict__ freq,
    const int*   __restrict__ targets,
    const int*   __restrict__ contexts,
    const int*   __restrict__ noises,
    float*       __restrict__ block_partials,
    int V, int E, int B, int NC)
{
    __shared__ float wave_part[4];
    const int wave = threadIdx.x >> 6;
    const int lane = threadIdx.x & 63;
    const int waves_total = gridDim.x * 4;

    float acc = 0.0f;  // this wave's contribution to the final scalar

    for (int j = blockIdx.x * 4 + wave; j < B; j += waves_total) {
        const int t = targets[j];
        const int c = contexts[j];

        float dot = 0.0f, sq = 0.0f;
        for (int e = lane; e < E; e += 64) {
            float qe = embed[(size_t)e * V + t];
            float re = embed[(size_t)e * V + c];
            dot = fmaf(qe, re, dot);
            sq  = fmaf(qe, qe, fmaf(re, re, sq));
        }
        // butterfly reduce across the 64-lane wave
        #pragma unroll
        for (int off = 32; off > 0; off >>= 1) {
            dot += __shfl_xor(dot, off, 64);
            sq  += __shfl_xor(sq,  off, 64);
        }

        const float s = (dot + bias[t]) / (float)E;

        float term = 0.0f;
        if (lane == 0) {
            term = log_sigmoid_f(s - logf((float)NC * freq[t]));
        }
        // noise terms: k-th noise for pair j sits at noises[j + k*B]
        for (int k = lane; k < NC; k += 64) {
            const int nidx = noises[j + (size_t)k * B];
            term += log_sigmoid_f(-(s - logf((float)NC * freq[nidx])));
        }
        #pragma unroll
        for (int off = 32; off > 0; off >>= 1) {
            term += __shfl_xor(term, off, 64);
        }

        if (lane == 0) {
            acc += -term / (float)B + 10.0f * sq / (float)(E * (size_t)B);
        }
    }

    if (lane == 0) wave_part[wave] = acc;
    __syncthreads();
    if (threadIdx.x == 0) {
        block_partials[blockIdx.x] =
            wave_part[0] + wave_part[1] + wave_part[2] + wave_part[3];
    }
}

__global__ __launch_bounds__(256) void reduce_partials_kernel(
    const float* __restrict__ parts, int n, float* __restrict__ out)
{
    __shared__ double sh[256];
    double a = 0.0;
    for (int i = threadIdx.x; i < n; i += 256) a += (double)parts[i];
    sh[threadIdx.x] = a;
    __syncthreads();
    for (int s = 128; s > 0; s >>= 1) {
        if (threadIdx.x < s) sh[threadIdx.x] += sh[threadIdx.x + s];
        __syncthreads();
    }
    if (threadIdx.x == 0) out[0] = (float)sh[0];
}

extern "C" void kernel_launch(void* const* d_in, const int* in_sizes, int n_in,
                              void* d_out, int out_size, void* d_ws, size_t ws_size,
                              hipStream_t stream) {
    const float* embed    = (const float*)d_in[0];
    const float* bias     = (const float*)d_in[1];
    const float* freq     = (const float*)d_in[2];
    const int*   targets  = (const int*)d_in[3];
    const int*   contexts = (const int*)d_in[4];
    const int*   noises   = (const int*)d_in[5];

    const int V  = in_sizes[2];              // vocab
    const int E  = in_sizes[0] / V;          // embed dim (128)
    const int B  = in_sizes[3];              // batch (16384)
    const int NC = in_sizes[5] / B;          // noise count (16)

    float* partials = (float*)d_ws;

    int nblocks = (B + 3) / 4;               // one wave per pair, 4 waves/block
    if (nblocks > 4096) nblocks = 4096;

    nce_pairs_kernel<<<nblocks, 256, 0, stream>>>(
        embed, bias, freq, targets, contexts, noises, partials, V, E, B, NC);

    reduce_partials_kernel<<<1, 256, 0, stream>>>(
        partials, nblocks, (float*)d_out);
}

// Round 2
// 90.978 us; speedup vs baseline: 1.1104x; 1.1104x over previous
//
#include <hip/hip_runtime.h>
#include <math.h>

// NCE loss: scalar output.
//   s_j = (q_j . r_j + bias[t_j]) / E
//   loss = sum_j log_sigmoid(s_j - log(NC*freq[t_j]))
//   noise_loss = sum_j sum_k log_sigmoid(-(s_j - log(NC*freq[noises[j + k*B]])))
//   out = -(loss + noise_loss)/B + 10*(sum q^2 + sum r^2)/(E*B)
//
// Layout: 256-thread block = 32 pairs x 8 e-chunks. Each thread gathers a
// 16-element slice of its pair's two embed columns (32 independent loads,
// lane-local accumulate -> no cross-lane ops on the gather critical path).

#define PAIRS 32
#define GSPLIT 8

__device__ __forceinline__ float log_sigmoid_f(float x) {
    // jax.nn.log_sigmoid(x) = min(x,0) - log1p(exp(-|x|))
    return fminf(x, 0.0f) - log1pf(expf(-fabsf(x)));
}

__global__ __launch_bounds__(256) void nce_kernel(
    const float* __restrict__ embed,
    const float* __restrict__ bias,
    const float* __restrict__ freq,
    const int*   __restrict__ targets,
    const int*   __restrict__ contexts,
    const int*   __restrict__ noises,
    float*       __restrict__ block_partials,
    int V, int E, int B, int NC)
{
    __shared__ float sh_dot[GSPLIT][PAIRS];
    __shared__ float sh_sq [GSPLIT][PAIRS];
    __shared__ float sh_s  [PAIRS];
    __shared__ float sh_pp [PAIRS];
    __shared__ float sh_n  [GSPLIT][PAIRS];

    const int p = threadIdx.x & (PAIRS - 1);
    const int g = threadIdx.x >> 5;          // 0..7
    const int j = blockIdx.x * PAIRS + p;
    const bool valid = (j < B);

    // ---- Phase A: partial dot / sumsq for (pair p, e-chunk g) ----
    float dot = 0.0f, sq = 0.0f;
    if (valid) {
        const int t = targets[j];
        const int c = contexts[j];
        const int epc = E / GSPLIT;          // 16 for E=128
        const int e0  = g * epc;
        const float* ct = embed + t;
        const float* cc = embed + c;
        #pragma unroll 8
        for (int e = e0; e < e0 + epc; ++e) {
            float qe = ct[(size_t)e * V];
            float re = cc[(size_t)e * V];
            dot = fmaf(qe, re, dot);
            sq  = fmaf(qe, qe, fmaf(re, re, sq));
        }
    }
    sh_dot[g][p] = dot;
    sh_sq [g][p] = sq;
    __syncthreads();

    // ---- Phase B: per-pair s, positive term, penalty (threads 0..31) ----
    if (threadIdx.x < PAIRS) {
        const int jp = blockIdx.x * PAIRS + threadIdx.x;
        float d = 0.0f, s2 = 0.0f;
        #pragma unroll
        for (int gg = 0; gg < GSPLIT; ++gg) {
            d  += sh_dot[gg][threadIdx.x];
            s2 += sh_sq [gg][threadIdx.x];
        }
        float sval = 0.0f, pp = 0.0f;
        if (jp < B) {
            const int t = targets[jp];
            sval = (d + bias[t]) / (float)E;
            const float pos = log_sigmoid_f(sval - logf((float)NC * freq[t]));
            pp = -pos / (float)B + 10.0f * s2 / ((float)E * (float)B);
        }
        sh_s [threadIdx.x] = sval;
        sh_pp[threadIdx.x] = pp;
    }
    __syncthreads();

    // ---- Phase C: noise terms; thread (p,g) handles k = g, g+8, ... ----
    float nacc = 0.0f;
    if (valid) {
        const float sval = sh_s[p];
        for (int k = g; k < NC; k += GSPLIT) {
            const int n = noises[j + (size_t)k * B];
            nacc += log_sigmoid_f(-(sval - logf((float)NC * freq[n])));
        }
    }
    sh_n[g][p] = nacc;
    __syncthreads();

    // ---- Phase D: block reduction ----
    if (threadIdx.x < PAIRS) {
        float a = sh_pp[threadIdx.x];
        float nsum = 0.0f;
        #pragma unroll
        for (int gg = 0; gg < GSPLIT; ++gg) nsum += sh_n[gg][threadIdx.x];
        a += -nsum / (float)B;
        #pragma unroll
        for (int off = 16; off > 0; off >>= 1) a += __shfl_xor(a, off, 64);
        if (threadIdx.x == 0) block_partials[blockIdx.x] = a;
    }
}

__global__ __launch_bounds__(256) void reduce_partials_kernel(
    const float* __restrict__ parts, int n, float* __restrict__ out)
{
    __shared__ double sh[256];
    double a = 0.0;
    for (int i = threadIdx.x; i < n; i += 256) a += (double)parts[i];
    sh[threadIdx.x] = a;
    __syncthreads();
    for (int s = 128; s > 0; s >>= 1) {
        if (threadIdx.x < s) sh[threadIdx.x] += sh[threadIdx.x + s];
        __syncthreads();
    }
    if (threadIdx.x == 0) out[0] = (float)sh[0];
}

extern "C" void kernel_launch(void* const* d_in, const int* in_sizes, int n_in,
                              void* d_out, int out_size, void* d_ws, size_t ws_size,
                              hipStream_t stream) {
    const float* embed    = (const float*)d_in[0];
    const float* bias     = (const float*)d_in[1];
    const float* freq     = (const float*)d_in[2];
    const int*   targets  = (const int*)d_in[3];
    const int*   contexts = (const int*)d_in[4];
    const int*   noises   = (const int*)d_in[5];

    const int V  = in_sizes[2];              // vocab (1e6)
    const int E  = in_sizes[0] / V;          // embed dim (128)
    const int B  = in_sizes[3];              // batch (16384)
    const int NC = in_sizes[5] / B;          // noise count (16)

    float* partials = (float*)d_ws;

    const int nblocks = (B + PAIRS - 1) / PAIRS;   // 512 for B=16384

    nce_kernel<<<nblocks, 256, 0, stream>>>(
        embed, bias, freq, targets, contexts, noises, partials, V, E, B, NC);

    reduce_partials_kernel<<<1, 256, 0, stream>>>(
        partials, nblocks, (float*)d_out);
}